// Round 7
// baseline (2343.240 us; speedup 1.0000x reference)
//
#include <hip/hip_runtime.h>
#include <hip/hip_bf16.h>
#include <math.h>
#include <stdint.h>

// Problem constants
#define E_ 8
#define R_ 32
#define D_ 1024
#define H_ 4096
#define NTOK 4096          // B*S
#define SCALING 0.03125f   // 1/R

__device__ __forceinline__ float gelu_exact(float v) {
    return 0.5f * v * (1.0f + erff(v * 0.70710678118654752f));
}

// ---------------------------------------------------------------------------
// Kernel 1: router. One wave per token, all-fp32. Outputs are FP32 now.
// routing -> out[NTOK*D + t*E + e], expert_choice -> out[NTOK*D + NTOK*E + ...]
// ---------------------------------------------------------------------------
__global__ __launch_bounds__(256) void k_router(
    const float* __restrict__ x, const float* __restrict__ rw,
    const float* __restrict__ rb,
    float* __restrict__ out, int* __restrict__ idx)
{
    const int wave = threadIdx.x >> 6, lane = threadIdx.x & 63;
    const int t = blockIdx.x * 4 + wave;
    const float4* xr = (const float4*)(x + (size_t)t * D_);
    float4 xv[4];
#pragma unroll
    for (int s = 0; s < 4; ++s) xv[s] = xr[lane + 64 * s];
    float acc[E_];
#pragma unroll
    for (int e = 0; e < E_; ++e) {
        const float4* wr = (const float4*)(rw + (size_t)e * D_);
        float s = 0.f;
#pragma unroll
        for (int u = 0; u < 4; ++u) {
            float4 wv = wr[lane + 64 * u];
            s += xv[u].x * wv.x + xv[u].y * wv.y + xv[u].z * wv.z + xv[u].w * wv.w;
        }
        acc[e] = s;
    }
#pragma unroll
    for (int e = 0; e < E_; ++e) {
#pragma unroll
        for (int m = 32; m > 0; m >>= 1) acc[e] += __shfl_xor(acc[e], m, 64);
        acc[e] += rb[e];
    }
    int best = 0;
#pragma unroll
    for (int e = 1; e < E_; ++e) if (acc[e] > acc[best]) best = e;   // first-max (np.argmax)
    const float mx = acc[best];
    float pr[E_]; float se = 0.f;
#pragma unroll
    for (int e = 0; e < E_; ++e) { pr[e] = expf(acc[e] - mx); se += pr[e]; }
    const float inv = 1.f / se;
    if (lane < E_) {
        float r = pr[lane] * inv;
        out[(size_t)NTOK * D_ + (size_t)t * E_ + lane] = r;
        float maskv = (lane == best) ? 1.f : 0.f;
        out[(size_t)NTOK * D_ + (size_t)NTOK * E_ + (size_t)t * E_ + lane] = (maskv - r) + r;
    }
    if (lane == 0) idx[t] = best;
}

// ---------------------------------------------------------------------------
// fp32 VALU tiled GEMM: C[m][n] = sum_k A[m][k]*W[n][k] + bias[n].
// 64x64 tile, 256 threads, 4x4 micro-tile. No activation (done downstream).
// ---------------------------------------------------------------------------
template <int KTOT>
__global__ __launch_bounds__(256) void k_gemm_f32(
    const float* __restrict__ A,     // [M, KTOT]
    const float* __restrict__ W,     // [N, KTOT]
    const float* __restrict__ bias,  // [N]
    float* __restrict__ C,           // [M, N]
    int N)
{
    __shared__ float As[64][17];
    __shared__ float Ws[64][17];
    const int tid = threadIdx.x;
    const int tx = tid & 15, ty = tid >> 4;
    const int m0 = blockIdx.y * 64, n0 = blockIdx.x * 64;
    float acc[4][4] = {};
    for (int k0 = 0; k0 < KTOT; k0 += 16) {
        __syncthreads();
        for (int l = tid; l < 1024; l += 256) {
            int i = l >> 4, kk = l & 15;
            As[i][kk] = A[(size_t)(m0 + i) * KTOT + k0 + kk];
            Ws[i][kk] = W[(size_t)(n0 + i) * KTOT + k0 + kk];
        }
        __syncthreads();
#pragma unroll
        for (int kk = 0; kk < 16; ++kk) {
            float ar[4], br[4];
#pragma unroll
            for (int a = 0; a < 4; ++a) ar[a] = As[ty * 4 + a][kk];
#pragma unroll
            for (int b = 0; b < 4; ++b) br[b] = Ws[tx * 4 + b][kk];
#pragma unroll
            for (int a = 0; a < 4; ++a)
#pragma unroll
                for (int b = 0; b < 4; ++b) acc[a][b] += ar[a] * br[b];
        }
    }
#pragma unroll
    for (int a = 0; a < 4; ++a) {
        int m = m0 + ty * 4 + a;
#pragma unroll
        for (int b = 0; b < 4; ++b) {
            int n = n0 + tx * 4 + b;
            C[(size_t)m * N + n] = acc[a][b] + bias[n];
        }
    }
}

// ---------------------------------------------------------------------------
// LoRA stage, one block (256 thr) per token.
// Stage A: hs[r] = dot(act[t, 0:KIN], A[e, r, 0:KIN]) + Ab[e, r]
// Stage B: for each of NOUTL outputs: io[t*NOUTL+h] (+)= SCALING*(hs.B[e,h,:]+Bb[e,h])
// DOWN=true:  io = down buffer; apply GELU after adding (produces a).
// DOWN=false: io = final out; in-place add (up += lora).
// ---------------------------------------------------------------------------
template <int KIN, int NOUTL, bool DOWN>
__global__ __launch_bounds__(256) void k_lora(
    const float* __restrict__ act,   // [NTOK, KIN] (x for down, a for up)
    const float* __restrict__ Aw,    // [E, 32, KIN]
    const float* __restrict__ Ab,    // [E, 32]
    const float* __restrict__ Bw,    // [E, NOUTL, 32]
    const float* __restrict__ Bb,    // [E, NOUTL]
    const int* __restrict__ idx,
    float* __restrict__ io)          // [NTOK, NOUTL]
{
    const int t = blockIdx.x;
    const int e = idx[t] & 7;
    const int tid = threadIdx.x;
    const int r = tid & 31, c = tid >> 5;          // 8 chunks
    __shared__ float part[8][32];
    __shared__ float hs[32];
    const int CH = KIN / 8;
    {
        const float* av = act + (size_t)t * KIN + c * CH;
        const float* wv = Aw + ((size_t)e * 32 + r) * KIN + c * CH;
        float s = 0.f;
        for (int d = 0; d < CH; ++d) s += av[d] * wv[d];
        part[c][r] = s;
    }
    __syncthreads();
    if (tid < 32) {
        float s = 0.f;
#pragma unroll
        for (int cc = 0; cc < 8; ++cc) s += part[cc][tid];
        hs[tid] = s + Ab[e * 32 + tid];
    }
    __syncthreads();
    for (int h = tid; h < NOUTL; h += 256) {
        const float* bw = Bw + ((size_t)e * NOUTL + h) * 32;
        float s = 0.f;
#pragma unroll
        for (int rr = 0; rr < 32; ++rr) s += hs[rr] * bw[rr];
        float v = io[(size_t)t * NOUTL + h] + SCALING * (s + Bb[(size_t)e * NOUTL + h]);
        io[(size_t)t * NOUTL + h] = DOWN ? gelu_exact(v) : v;
    }
}

// ---------------------------------------------------------------------------
// Workspace layout (bytes). 1 MiB control + 64 MiB activation buffer.
// ---------------------------------------------------------------------------
#define OFF_IDX      0u
#define OFF_BUF      1048576u       // [NTOK, H] fp32 = 64 MiB (down, then a)
#define WS_NEEDED    68157440u

extern "C" void kernel_launch(void* const* d_in, const int* in_sizes, int n_in,
                              void* d_out, int out_size, void* d_ws, size_t ws_size,
                              hipStream_t stream)
{
    (void)out_size;
    if (ws_size < (size_t)WS_NEEDED) return;
    // Input-model guard: if sizes mismatch, write nothing -> absmax 2.703125
    // (distinguishable signal that the input ordering model is wrong).
    if (n_in < 15 || in_sizes[0] != NTOK * D_ || in_sizes[3] != H_ * D_ ||
        in_sizes[5] != D_ * H_ || in_sizes[9] != E_ * H_ * R_) return;

    const float* x   = (const float*)d_in[0];
    const float* rw  = (const float*)d_in[1];
    const float* rb  = (const float*)d_in[2];
    const float* w1  = (const float*)d_in[3];
    const float* b1  = (const float*)d_in[4];
    const float* w2  = (const float*)d_in[5];
    const float* b2  = (const float*)d_in[6];
    const float* Ad  = (const float*)d_in[7];
    const float* Abd = (const float*)d_in[8];
    const float* Bd  = (const float*)d_in[9];
    const float* Bbd = (const float*)d_in[10];
    const float* Au  = (const float*)d_in[11];
    const float* Abu = (const float*)d_in[12];
    const float* Bu  = (const float*)d_in[13];
    const float* Bbu = (const float*)d_in[14];
    float* out = (float*)d_out;   // fp32 outputs (reference is all-fp32)
    char* ws = (char*)d_ws;

    int* idx   = (int*)(ws + OFF_IDX);
    float* buf = (float*)(ws + OFF_BUF);   // down -> (lora+gelu) -> a

    k_router<<<NTOK / 4, 256, 0, stream>>>(x, rw, rb, out, idx);

    // down = x @ w1^T + b1
    k_gemm_f32<D_><<<dim3(H_ / 64, NTOK / 64), 256, 0, stream>>>(x, w1, b1, buf, H_);
    // down += lora_down; a = gelu(down)   (in-place on buf)
    k_lora<D_, H_, true><<<NTOK, 256, 0, stream>>>(x, Ad, Abd, Bd, Bbd, idx, buf);
    // up = a @ w2^T + b2
    k_gemm_f32<H_><<<dim3(D_ / 64, NTOK / 64), 256, 0, stream>>>(buf, w2, b2, out, D_);
    // up += lora_up   (in-place on out)
    k_lora<H_, D_, false><<<NTOK, 256, 0, stream>>>(buf, Au, Abu, Bu, Bbu, idx, out);
}

// Round 8
// 405.853 us; speedup vs baseline: 5.7736x; 5.7736x over previous
//
#include <hip/hip_runtime.h>
#include <hip/hip_bf16.h>
#include <math.h>
#include <stdint.h>

// Problem constants
#define E_ 8
#define R_ 32
#define D_ 1024
#define H_ 4096
#define NTOK 4096          // B*S
#define M_MAX 5120         // padded-token capacity (40 tiles of 128)
#define TILES_MAX 40
#define SCALING 0.03125f   // 1/R

typedef __attribute__((ext_vector_type(8))) __bf16 bf16x8;
typedef __attribute__((ext_vector_type(8))) unsigned short ushort8;
typedef __attribute__((ext_vector_type(4))) float floatx4;

__device__ __forceinline__ unsigned short f2b(float f) {
    union { float f; unsigned int i; } v; v.f = f;
    unsigned int x = v.i;
    x += 0x7fffu + ((x >> 16) & 1u);   // round-to-nearest-even
    return (unsigned short)(x >> 16);
}
__device__ __forceinline__ float gelu_exact(float v) {
    return 0.5f * v * (1.0f + erff(v * 0.70710678118654752f));
}

// ---------------------------------------------------------------------------
// Kernel 0: fp32 -> bf16 conversion (weights). 8 elems/thread, n % 2048 == 0.
// ---------------------------------------------------------------------------
__global__ __launch_bounds__(256) void k_cvt(
    const float* __restrict__ in, unsigned short* __restrict__ outb, int n)
{
    int i = (blockIdx.x * 256 + threadIdx.x) * 8;
    if (i >= n) return;
    float4 a = *(const float4*)(in + i);
    float4 b = *(const float4*)(in + i + 4);
    ushort8 o;
    o[0] = f2b(a.x); o[1] = f2b(a.y); o[2] = f2b(a.z); o[3] = f2b(a.w);
    o[4] = f2b(b.x); o[5] = f2b(b.y); o[6] = f2b(b.z); o[7] = f2b(b.w);
    *(ushort8*)(outb + i) = o;
}

// ---------------------------------------------------------------------------
// Kernel 1: router. One wave per token, all-fp32. FP32 outputs:
// routing -> out[NTOK*D + t*E + e]; expert_choice -> out[NTOK*D + NTOK*E + ...]
// ---------------------------------------------------------------------------
__global__ __launch_bounds__(256) void k_router(
    const float* __restrict__ x, const float* __restrict__ rw,
    const float* __restrict__ rb,
    float* __restrict__ out, int* __restrict__ idx)
{
    const int wave = threadIdx.x >> 6, lane = threadIdx.x & 63;
    const int t = blockIdx.x * 4 + wave;
    const float4* xr = (const float4*)(x + (size_t)t * D_);
    float4 xv[4];
#pragma unroll
    for (int s = 0; s < 4; ++s) xv[s] = xr[lane + 64 * s];
    float acc[E_];
#pragma unroll
    for (int e = 0; e < E_; ++e) {
        const float4* wr = (const float4*)(rw + (size_t)e * D_);
        float s = 0.f;
#pragma unroll
        for (int u = 0; u < 4; ++u) {
            float4 wv = wr[lane + 64 * u];
            s += xv[u].x * wv.x + xv[u].y * wv.y + xv[u].z * wv.z + xv[u].w * wv.w;
        }
        acc[e] = s;
    }
#pragma unroll
    for (int e = 0; e < E_; ++e) {
#pragma unroll
        for (int m = 32; m > 0; m >>= 1) acc[e] += __shfl_xor(acc[e], m, 64);
        acc[e] += rb[e];
    }
    int best = 0;
#pragma unroll
    for (int e = 1; e < E_; ++e) if (acc[e] > acc[best]) best = e;   // first-max (np.argmax)
    const float mx = acc[best];
    float pr[E_]; float se = 0.f;
#pragma unroll
    for (int e = 0; e < E_; ++e) { pr[e] = expf(acc[e] - mx); se += pr[e]; }
    const float inv = 1.f / se;
    if (lane < E_) {
        float r = pr[lane] * inv;
        out[(size_t)NTOK * D_ + (size_t)t * E_ + lane] = r;
        float maskv = (lane == best) ? 1.f : 0.f;
        out[(size_t)NTOK * D_ + (size_t)NTOK * E_ + (size_t)t * E_ + lane] = (maskv - r) + r;
    }
    if (lane == 0) idx[t] = best;
}

// ---------------------------------------------------------------------------
// Kernel 2: scan (1 block). Deterministic expert-sorted permutation, segments
// padded to multiples of 128 so every GEMM tile has a uniform expert.
// ---------------------------------------------------------------------------
__global__ __launch_bounds__(256) void k_scan(
    const int* __restrict__ idx, int* __restrict__ hdr,
    int* __restrict__ tile_e, int* __restrict__ gather)
{
    __shared__ int cnt[256][E_];
    __shared__ int tot[E_], base[E_];
    const int tid = threadIdx.x;
    for (int m = tid; m < M_MAX; m += 256) gather[m] = -1;
    int c[E_];
#pragma unroll
    for (int e = 0; e < E_; ++e) c[e] = 0;
    for (int t = tid * 16; t < tid * 16 + 16; ++t) c[idx[t] & 7]++;
#pragma unroll
    for (int e = 0; e < E_; ++e) cnt[tid][e] = c[e];
    __syncthreads();
    if (tid < E_) {
        int run = 0;
        for (int i = 0; i < 256; ++i) { int v = cnt[i][tid]; cnt[i][tid] = run; run += v; }
        tot[tid] = run;
    }
    __syncthreads();
    if (tid == 0) {
        int b = 0, tp = 0;
        for (int e = 0; e < E_; ++e) {
            base[e] = b;
            int nt = (tot[e] + 127) >> 7;
            for (int k = 0; k < nt; ++k) tile_e[tp++] = e;
            b += nt << 7;
        }
        hdr[0] = b;       // M_pad
        hdr[1] = tp;      // n_tiles
        for (int k = tp; k < TILES_MAX; ++k) tile_e[k] = 0;
    }
    __syncthreads();
    int p[E_];
#pragma unroll
    for (int e = 0; e < E_; ++e) p[e] = base[e] + cnt[tid][e];
    for (int t = tid * 16; t < tid * 16 + 16; ++t) { int e = idx[t] & 7; gather[p[e]++] = t; }
}

// ---------------------------------------------------------------------------
// Kernel 3: gather x rows (fp32) into expert-sorted bf16 Xg (zeros for pads).
// ---------------------------------------------------------------------------
__global__ __launch_bounds__(128) void k_gather(
    const float* __restrict__ x, const int* __restrict__ gather,
    unsigned short* __restrict__ xg)
{
    const int m = blockIdx.x, tid = threadIdx.x;
    const int t = gather[m];
    ushort8* dst = (ushort8*)(xg + (size_t)m * D_);
    ushort8 o;
    if ((unsigned)t < (unsigned)NTOK) {
        const float4* src = (const float4*)(x + (size_t)t * D_);
        float4 a = src[tid * 2], b = src[tid * 2 + 1];
        o[0] = f2b(a.x); o[1] = f2b(a.y); o[2] = f2b(a.z); o[3] = f2b(a.w);
        o[4] = f2b(b.x); o[5] = f2b(b.y); o[6] = f2b(b.z); o[7] = f2b(b.w);
    } else {
        o = (ushort8)(0);
    }
    dst[tid] = o;
}

// ---------------------------------------------------------------------------
// Kernel 4/6: LoRA A-stage, split-K. [128,Ktot] x [32,Ktot]^T -> fp32 partials.
// Per-tile expert is uniform (sorted+padded). grid = (nsplit, TILES_MAX).
// ---------------------------------------------------------------------------
__global__ __launch_bounds__(256) void k_lora_a(
    const unsigned short* __restrict__ A,    // [M_MAX, Ktot] bf16 (Xg or a_g)
    const unsigned short* __restrict__ W,    // [E, 32, Ktot] bf16 (converted)
    const int* __restrict__ hdr, const int* __restrict__ tile_e,
    float* __restrict__ part,                // [nsplit, M_MAX, 32]
    int Ktot, int Kslice)
{
    const int mtile = blockIdx.y;
    int ntiles = hdr[1]; if (ntiles > TILES_MAX) ntiles = TILES_MAX;
    if (mtile >= ntiles) return;
    const int e = tile_e[mtile] & 7;
    const int kbase = blockIdx.x * Kslice;
    const int wave = threadIdx.x >> 6, lane = threadIdx.x & 63;
    const int q = lane >> 4, l16 = lane & 15;
    const int m0 = mtile * 128;
    const floatx4 z4 = {0.f, 0.f, 0.f, 0.f};
    floatx4 acc[2][2] = {{z4, z4}, {z4, z4}};
    const bf16x8* A0 = (const bf16x8*)(A + (size_t)(m0 + wave * 32 + l16) * Ktot);
    const bf16x8* A1 = (const bf16x8*)(A + (size_t)(m0 + wave * 32 + 16 + l16) * Ktot);
    const bf16x8* W0 = (const bf16x8*)(W + ((size_t)e * 32 + l16) * Ktot);
    const bf16x8* W1 = (const bf16x8*)(W + ((size_t)e * 32 + 16 + l16) * Ktot);
    for (int k = kbase; k < kbase + Kslice; k += 32) {
        int u = (k >> 3) + q;
        bf16x8 a0 = A0[u], a1 = A1[u];
        bf16x8 b0 = W0[u], b1 = W1[u];
        acc[0][0] = __builtin_amdgcn_mfma_f32_16x16x32_bf16(a0, b0, acc[0][0], 0, 0, 0);
        acc[0][1] = __builtin_amdgcn_mfma_f32_16x16x32_bf16(a0, b1, acc[0][1], 0, 0, 0);
        acc[1][0] = __builtin_amdgcn_mfma_f32_16x16x32_bf16(a1, b0, acc[1][0], 0, 0, 0);
        acc[1][1] = __builtin_amdgcn_mfma_f32_16x16x32_bf16(a1, b1, acc[1][1], 0, 0, 0);
    }
    float* pp = part + (size_t)blockIdx.x * M_MAX * 32;
#pragma unroll
    for (int mi = 0; mi < 2; ++mi)
#pragma unroll
        for (int ni = 0; ni < 2; ++ni)
#pragma unroll
            for (int r = 0; r < 4; ++r) {
                int gm = m0 + wave * 32 + mi * 16 + q * 4 + r;
                int gc = ni * 16 + l16;
                pp[(size_t)gm * 32 + gc] = acc[mi][ni][r];
            }
}

// Kernel 5/7: finalize LoRA A-stage: sum split-K partials, add Ab (fp32),
// pre-scale by 1/R, store bf16 [M_MAX,32].
__global__ __launch_bounds__(256) void k_lora_fin(
    const float* __restrict__ part, const float* __restrict__ Ab,
    const int* __restrict__ hdr, const int* __restrict__ tile_e,
    unsigned short* __restrict__ outb, int nsplit)
{
    const int mtile = blockIdx.x;
    int ntiles = hdr[1]; if (ntiles > TILES_MAX) ntiles = TILES_MAX;
    if (mtile >= ntiles) return;
    const int e = tile_e[mtile] & 7;
    for (int i = threadIdx.x; i < 128 * 32; i += 256) {
        int lr = i >> 5, r = i & 31;
        size_t o = ((size_t)(mtile * 128 + lr)) * 32 + r;
        float s = 0.f;
        for (int p = 0; p < nsplit; ++p) s += part[(size_t)p * M_MAX * 32 + o];
        outb[o] = f2b(SCALING * (s + Ab[e * 32 + r]));
    }
}

// ---------------------------------------------------------------------------
// Main GEMM: 128x128 tile, BK=64. Register staging (coalesced dwordx4 load ->
// ds_write_b128) into XOR-swizzled LDS, mfma_f32_16x16x32_bf16, fused LoRA-B
// (one K=32 MFMA into the same accumulators) + fp32 bias.
// fc1: GELU -> bf16 a_g. fc2: fp32 scatter to token-order d_out.
// ---------------------------------------------------------------------------
template <int KTOT, bool IS_FC1>
__global__ __launch_bounds__(256) void k_mlp(
    const unsigned short* __restrict__ Amat,   // [M_MAX, KTOT] bf16
    const unsigned short* __restrict__ Wmat,   // [NOUT, KTOT] bf16 (NT layout)
    const float* __restrict__ bias,            // [NOUT] fp32
    const unsigned short* __restrict__ lora_h, // [M_MAX, 32] pre-scaled bf16
    const unsigned short* __restrict__ lora_B, // [E, NOUT, 32] bf16
    const float* __restrict__ lora_b,          // [E, NOUT] fp32
    const int* __restrict__ hdr, const int* __restrict__ tile_e,
    const int* __restrict__ gather,
    unsigned short* __restrict__ outb,         // fc1: a_g bf16
    float* __restrict__ outf,                  // fc2: d_out fp32
    int NOUT)
{
    const int mtile = blockIdx.y;
    int ntiles = hdr[1]; if (ntiles > TILES_MAX) ntiles = TILES_MAX;
    if (mtile >= ntiles) return;
    const int e = tile_e[mtile] & 7;
    const int h0 = blockIdx.x * 128;
    const int m0 = mtile * 128;
    // 128 rows x 8 units(16B); slot (row, j) holds global column-unit j^(row&7)
    __shared__ bf16x8 As[1024];
    __shared__ bf16x8 Bs[1024];
    const int tid = threadIdx.x;
    const int lane = tid & 63;
    const int q = lane >> 4, l16 = lane & 15;
    const int wave = tid >> 6;
    const int wm = wave & 1, wn = wave >> 1;
    const floatx4 z4 = {0.f, 0.f, 0.f, 0.f};
    floatx4 acc[4][4];
#pragma unroll
    for (int mi = 0; mi < 4; ++mi)
#pragma unroll
        for (int ni = 0; ni < 4; ++ni) acc[mi][ni] = z4;

    const unsigned short* Abase = Amat + (size_t)m0 * KTOT;
    const unsigned short* Bbase = Wmat + (size_t)h0 * KTOT;

    for (int k0 = 0; k0 < KTOT; k0 += 64) {
        bf16x8 va[4], vb[4];
#pragma unroll
        for (int rnd = 0; rnd < 4; ++rnd) {
            int s = rnd * 256 + tid;
            int row = s >> 3, j = s & 7;
            va[rnd] = *(const bf16x8*)(Abase + (size_t)row * KTOT + k0 + j * 8);
            vb[rnd] = *(const bf16x8*)(Bbase + (size_t)row * KTOT + k0 + j * 8);
        }
#pragma unroll
        for (int rnd = 0; rnd < 4; ++rnd) {
            int s = rnd * 256 + tid;
            int row = s >> 3, j = s & 7;
            int slot = row * 8 + (j ^ (row & 7));
            As[slot] = va[rnd];
            Bs[slot] = vb[rnd];
        }
        __syncthreads();
#pragma unroll
        for (int ka = 0; ka < 2; ++ka) {
            bf16x8 af[4], bfr[4];
#pragma unroll
            for (int mi = 0; mi < 4; ++mi) {
                int row = wm * 64 + mi * 16 + l16;
                af[mi] = As[row * 8 + ((ka * 4 + q) ^ (row & 7))];
            }
#pragma unroll
            for (int ni = 0; ni < 4; ++ni) {
                int row = wn * 64 + ni * 16 + l16;
                bfr[ni] = Bs[row * 8 + ((ka * 4 + q) ^ (row & 7))];
            }
#pragma unroll
            for (int mi = 0; mi < 4; ++mi)
#pragma unroll
                for (int ni = 0; ni < 4; ++ni)
                    acc[mi][ni] = __builtin_amdgcn_mfma_f32_16x16x32_bf16(af[mi], bfr[ni], acc[mi][ni], 0, 0, 0);
        }
        __syncthreads();
    }

    // Fused LoRA-B: one K=32 MFMA per subtile into the same accumulators.
    {
        bf16x8 a2[4], b2[4];
#pragma unroll
        for (int mi = 0; mi < 4; ++mi)
            a2[mi] = *(const bf16x8*)(lora_h + (size_t)(m0 + wm * 64 + mi * 16 + l16) * 32 + q * 8);
#pragma unroll
        for (int ni = 0; ni < 4; ++ni)
            b2[ni] = *(const bf16x8*)(lora_B + ((size_t)e * NOUT + h0 + wn * 64 + ni * 16 + l16) * 32 + q * 8);
#pragma unroll
        for (int mi = 0; mi < 4; ++mi)
#pragma unroll
            for (int ni = 0; ni < 4; ++ni)
                acc[mi][ni] = __builtin_amdgcn_mfma_f32_16x16x32_bf16(a2[mi], b2[ni], acc[mi][ni], 0, 0, 0);
    }

#pragma unroll
    for (int ni = 0; ni < 4; ++ni) {
        int gh = h0 + wn * 64 + ni * 16 + l16;
        float bv = bias[gh] + SCALING * lora_b[e * NOUT + gh];
#pragma unroll
        for (int mi = 0; mi < 4; ++mi) {
#pragma unroll
            for (int r = 0; r < 4; ++r) {
                int gm = m0 + wm * 64 + mi * 16 + q * 4 + r;
                float v = acc[mi][ni][r] + bv;
                if (IS_FC1) {
                    outb[(size_t)gm * NOUT + gh] = f2b(gelu_exact(v));
                } else {
                    int t = gather[gm];
                    if ((unsigned)t < (unsigned)NTOK) outf[(size_t)t * NOUT + gh] = v;
                }
            }
        }
    }
}

// ---------------------------------------------------------------------------
// Workspace layout (bytes). Total ~79.2 MiB.
// ---------------------------------------------------------------------------
#define OFF_IDX      0u
#define OFF_HDR      16384u
#define OFF_TILE     16640u
#define OFF_GATHER   16896u
#define OFF_XG       37376u
#define OFF_HSELP    10523136u
#define OFF_HSELB    13144576u
#define OFF_AG       13472256u
#define OFF_HUPP     55415296u
#define OFF_HUPB     60658176u
#define OFF_W1B      60985856u
#define OFF_W2B      69374464u
#define OFF_ADB      77763072u
#define OFF_BDB      78287360u
#define OFF_AUB      80384512u
#define OFF_BUB      82481664u
#define WS_NEEDED    83005952u

extern "C" void kernel_launch(void* const* d_in, const int* in_sizes, int n_in,
                              void* d_out, int out_size, void* d_ws, size_t ws_size,
                              hipStream_t stream)
{
    (void)out_size;
    if (ws_size < (size_t)WS_NEEDED) return;
    if (n_in < 15 || in_sizes[0] != NTOK * D_ || in_sizes[3] != H_ * D_ ||
        in_sizes[5] != D_ * H_ || in_sizes[9] != E_ * H_ * R_) return;

    const float* x   = (const float*)d_in[0];
    const float* rw  = (const float*)d_in[1];
    const float* rb  = (const float*)d_in[2];
    const float* w1  = (const float*)d_in[3];
    const float* b1  = (const float*)d_in[4];
    const float* w2  = (const float*)d_in[5];
    const float* b2  = (const float*)d_in[6];
    const float* Ad  = (const float*)d_in[7];
    const float* Abd = (const float*)d_in[8];
    const float* Bd  = (const float*)d_in[9];
    const float* Bbd = (const float*)d_in[10];
    const float* Au  = (const float*)d_in[11];
    const float* Abu = (const float*)d_in[12];
    const float* Bu  = (const float*)d_in[13];
    const float* Bbu = (const float*)d_in[14];
    float* out = (float*)d_out;   // fp32 outputs (reference is all-fp32)
    char* ws = (char*)d_ws;

    int* idx            = (int*)(ws + OFF_IDX);
    int* hdr            = (int*)(ws + OFF_HDR);
    int* tile_e         = (int*)(ws + OFF_TILE);
    int* gather         = (int*)(ws + OFF_GATHER);
    unsigned short* xg  = (unsigned short*)(ws + OFF_XG);
    float* hselp        = (float*)(ws + OFF_HSELP);
    unsigned short* hsb = (unsigned short*)(ws + OFF_HSELB);
    unsigned short* ag  = (unsigned short*)(ws + OFF_AG);
    float* hupp         = (float*)(ws + OFF_HUPP);
    unsigned short* hub = (unsigned short*)(ws + OFF_HUPB);
    unsigned short* w1b = (unsigned short*)(ws + OFF_W1B);
    unsigned short* w2b = (unsigned short*)(ws + OFF_W2B);
    unsigned short* Adb = (unsigned short*)(ws + OFF_ADB);
    unsigned short* Bdb = (unsigned short*)(ws + OFF_BDB);
    unsigned short* Aub = (unsigned short*)(ws + OFF_AUB);
    unsigned short* Bub = (unsigned short*)(ws + OFF_BUB);

    // fp32 -> bf16 weight conversions
    k_cvt<<<(H_ * D_) / 2048, 256, 0, stream>>>(w1, w1b, H_ * D_);
    k_cvt<<<(D_ * H_) / 2048, 256, 0, stream>>>(w2, w2b, D_ * H_);
    k_cvt<<<(E_ * R_ * D_) / 2048, 256, 0, stream>>>(Ad, Adb, E_ * R_ * D_);
    k_cvt<<<(E_ * H_ * R_) / 2048, 256, 0, stream>>>(Bd, Bdb, E_ * H_ * R_);
    k_cvt<<<(E_ * R_ * H_) / 2048, 256, 0, stream>>>(Au, Aub, E_ * R_ * H_);
    k_cvt<<<(E_ * D_ * R_) / 2048, 256, 0, stream>>>(Bu, Bub, E_ * D_ * R_);

    k_router<<<NTOK / 4, 256, 0, stream>>>(x, rw, rb, out, idx);
    k_scan<<<1, 256, 0, stream>>>(idx, hdr, tile_e, gather);
    k_gather<<<M_MAX, 128, 0, stream>>>(x, gather, xg);
    k_lora_a<<<dim3(4, TILES_MAX), 256, 0, stream>>>(xg, Adb, hdr, tile_e, hselp, D_, 256);
    k_lora_fin<<<TILES_MAX, 256, 0, stream>>>(hselp, Abd, hdr, tile_e, hsb, 4);
    k_mlp<D_, true><<<dim3(H_ / 128, TILES_MAX), 256, 0, stream>>>(
        xg, w1b, b1, hsb, Bdb, Bbd, hdr, tile_e, gather, ag, nullptr, H_);
    k_lora_a<<<dim3(8, TILES_MAX), 256, 0, stream>>>(ag, Aub, hdr, tile_e, hupp, H_, 512);
    k_lora_fin<<<TILES_MAX, 256, 0, stream>>>(hupp, Abu, hdr, tile_e, hub, 8);
    k_mlp<H_, false><<<dim3(D_ / 128, TILES_MAX), 256, 0, stream>>>(
        ag, w2b, b2, hub, Bub, Bbu, hdr, tile_e, gather, nullptr, out, D_);
}

// Round 9
// 330.174 us; speedup vs baseline: 7.0970x; 1.2292x over previous
//
#include <hip/hip_runtime.h>
#include <hip/hip_bf16.h>
#include <math.h>
#include <stdint.h>

// Problem constants
#define E_ 8
#define R_ 32
#define D_ 1024
#define H_ 4096
#define NTOK 4096          // B*S
#define M_MAX 5120         // padded-token capacity (40 tiles of 128)
#define TILES_MAX 40
#define SCALING 0.03125f   // 1/R

typedef __attribute__((ext_vector_type(8))) __bf16 bf16x8;
typedef __attribute__((ext_vector_type(8))) unsigned short ushort8;
typedef __attribute__((ext_vector_type(4))) float floatx4;

__device__ __forceinline__ unsigned short f2b(float f) {
    union { float f; unsigned int i; } v; v.f = f;
    unsigned int x = v.i;
    x += 0x7fffu + ((x >> 16) & 1u);   // round-to-nearest-even
    return (unsigned short)(x >> 16);
}
__device__ __forceinline__ float gelu_exact(float v) {
    return 0.5f * v * (1.0f + erff(v * 0.70710678118654752f));
}

#define GLOAD_LDS16(g, l) __builtin_amdgcn_global_load_lds( \
    (const __attribute__((address_space(1))) void*)(g),     \
    (__attribute__((address_space(3))) void*)(l), 16, 0, 0)

// ---------------------------------------------------------------------------
// Kernel 0: fused fp32 -> bf16 conversion of all six weight tensors.
// Segment boundaries (elements): w1 4194304 | w2 4194304 | Ad 262144 |
// Bd 1048576 | Au 1048576 | Bu 262144. Total 11010048 (= 5376 blocks x 2048).
// ---------------------------------------------------------------------------
__global__ __launch_bounds__(256) void k_cvt_all(
    const float* __restrict__ w1, const float* __restrict__ w2,
    const float* __restrict__ Ad, const float* __restrict__ Bd,
    const float* __restrict__ Au, const float* __restrict__ Bu,
    unsigned short* __restrict__ w1b, unsigned short* __restrict__ w2b,
    unsigned short* __restrict__ Adb, unsigned short* __restrict__ Bdb,
    unsigned short* __restrict__ Aub, unsigned short* __restrict__ Bub)
{
    long g = ((long)blockIdx.x * 256 + threadIdx.x) * 8;
    const float* src; unsigned short* dst; long off;
    if      (g <  4194304L) { src = w1; dst = w1b; off = 0; }
    else if (g <  8388608L) { src = w2; dst = w2b; off = 4194304L; }
    else if (g <  8650752L) { src = Ad; dst = Adb; off = 8388608L; }
    else if (g <  9699328L) { src = Bd; dst = Bdb; off = 8650752L; }
    else if (g < 10747904L) { src = Au; dst = Aub; off = 9699328L; }
    else                    { src = Bu; dst = Bub; off = 10747904L; }
    long i = g - off;
    float4 a = *(const float4*)(src + i);
    float4 b = *(const float4*)(src + i + 4);
    ushort8 o;
    o[0] = f2b(a.x); o[1] = f2b(a.y); o[2] = f2b(a.z); o[3] = f2b(a.w);
    o[4] = f2b(b.x); o[5] = f2b(b.y); o[6] = f2b(b.z); o[7] = f2b(b.w);
    *(ushort8*)(dst + i) = o;
}

// ---------------------------------------------------------------------------
// Kernel 1: router. One wave per token, all-fp32. FP32 outputs.
// ---------------------------------------------------------------------------
__global__ __launch_bounds__(256) void k_router(
    const float* __restrict__ x, const float* __restrict__ rw,
    const float* __restrict__ rb,
    float* __restrict__ out, int* __restrict__ idx)
{
    const int wave = threadIdx.x >> 6, lane = threadIdx.x & 63;
    const int t = blockIdx.x * 4 + wave;
    const float4* xr = (const float4*)(x + (size_t)t * D_);
    float4 xv[4];
#pragma unroll
    for (int s = 0; s < 4; ++s) xv[s] = xr[lane + 64 * s];
    float acc[E_];
#pragma unroll
    for (int e = 0; e < E_; ++e) {
        const float4* wr = (const float4*)(rw + (size_t)e * D_);
        float s = 0.f;
#pragma unroll
        for (int u = 0; u < 4; ++u) {
            float4 wv = wr[lane + 64 * u];
            s += xv[u].x * wv.x + xv[u].y * wv.y + xv[u].z * wv.z + xv[u].w * wv.w;
        }
        acc[e] = s;
    }
#pragma unroll
    for (int e = 0; e < E_; ++e) {
#pragma unroll
        for (int m = 32; m > 0; m >>= 1) acc[e] += __shfl_xor(acc[e], m, 64);
        acc[e] += rb[e];
    }
    int best = 0;
#pragma unroll
    for (int e = 1; e < E_; ++e) if (acc[e] > acc[best]) best = e;   // first-max (np.argmax)
    const float mx = acc[best];
    float pr[E_]; float se = 0.f;
#pragma unroll
    for (int e = 0; e < E_; ++e) { pr[e] = expf(acc[e] - mx); se += pr[e]; }
    const float inv = 1.f / se;
    if (lane < E_) {
        float r = pr[lane] * inv;
        out[(size_t)NTOK * D_ + (size_t)t * E_ + lane] = r;
        float maskv = (lane == best) ? 1.f : 0.f;
        out[(size_t)NTOK * D_ + (size_t)NTOK * E_ + (size_t)t * E_ + lane] = (maskv - r) + r;
    }
    if (lane == 0) idx[t] = best;
}

// ---------------------------------------------------------------------------
// Kernel 2: scan (1 block). Deterministic expert-sorted permutation, segments
// padded to multiples of 128 so every GEMM tile has a uniform expert.
// ---------------------------------------------------------------------------
__global__ __launch_bounds__(256) void k_scan(
    const int* __restrict__ idx, int* __restrict__ hdr,
    int* __restrict__ tile_e, int* __restrict__ gather)
{
    __shared__ int cnt[256][E_];
    __shared__ int tot[E_], base[E_];
    const int tid = threadIdx.x;
    for (int m = tid; m < M_MAX; m += 256) gather[m] = -1;
    int c[E_];
#pragma unroll
    for (int e = 0; e < E_; ++e) c[e] = 0;
    for (int t = tid * 16; t < tid * 16 + 16; ++t) c[idx[t] & 7]++;
#pragma unroll
    for (int e = 0; e < E_; ++e) cnt[tid][e] = c[e];
    __syncthreads();
    if (tid < E_) {
        int run = 0;
        for (int i = 0; i < 256; ++i) { int v = cnt[i][tid]; cnt[i][tid] = run; run += v; }
        tot[tid] = run;
    }
    __syncthreads();
    if (tid == 0) {
        int b = 0, tp = 0;
        for (int e = 0; e < E_; ++e) {
            base[e] = b;
            int nt = (tot[e] + 127) >> 7;
            for (int k = 0; k < nt; ++k) tile_e[tp++] = e;
            b += nt << 7;
        }
        hdr[0] = b;       // M_pad
        hdr[1] = tp;      // n_tiles
        for (int k = tp; k < TILES_MAX; ++k) tile_e[k] = 0;
    }
    __syncthreads();
    int p[E_];
#pragma unroll
    for (int e = 0; e < E_; ++e) p[e] = base[e] + cnt[tid][e];
    for (int t = tid * 16; t < tid * 16 + 16; ++t) { int e = idx[t] & 7; gather[p[e]++] = t; }
}

// ---------------------------------------------------------------------------
// Kernel 3: gather x rows (fp32) into expert-sorted bf16 Xg (zeros for pads).
// ---------------------------------------------------------------------------
__global__ __launch_bounds__(128) void k_gather(
    const float* __restrict__ x, const int* __restrict__ gather,
    unsigned short* __restrict__ xg)
{
    const int m = blockIdx.x, tid = threadIdx.x;
    const int t = gather[m];
    ushort8* dst = (ushort8*)(xg + (size_t)m * D_);
    ushort8 o;
    if ((unsigned)t < (unsigned)NTOK) {
        const float4* src = (const float4*)(x + (size_t)t * D_);
        float4 a = src[tid * 2], b = src[tid * 2 + 1];
        o[0] = f2b(a.x); o[1] = f2b(a.y); o[2] = f2b(a.z); o[3] = f2b(a.w);
        o[4] = f2b(b.x); o[5] = f2b(b.y); o[6] = f2b(b.z); o[7] = f2b(b.w);
    } else {
        o = (ushort8)(0);
    }
    dst[tid] = o;
}

// ---------------------------------------------------------------------------
// Kernel 4/6: LoRA A-stage, single pass. Block = 32 m-rows x 32 ranks; the 4
// waves split K, LDS-reduce, add Ab, pre-scale by 1/R, write bf16 [M_MAX,32].
// grid = (4, TILES_MAX). Replaces split-K partials + finalize kernels.
// ---------------------------------------------------------------------------
__global__ __launch_bounds__(256) void k_lora_a2(
    const unsigned short* __restrict__ A,    // [M_MAX, Ktot] bf16 (Xg or a_g)
    const unsigned short* __restrict__ W,    // [E, 32, Ktot] bf16 (converted)
    const float* __restrict__ Ab,            // [E, 32] fp32
    const int* __restrict__ hdr, const int* __restrict__ tile_e,
    unsigned short* __restrict__ outb,       // [M_MAX, 32] bf16 pre-scaled
    int Ktot)
{
    const int mtile = blockIdx.y;
    int ntiles = hdr[1]; if (ntiles > TILES_MAX) ntiles = TILES_MAX;
    if (mtile >= ntiles) return;
    const int e = tile_e[mtile] & 7;
    const int m0 = mtile * 128 + blockIdx.x * 32;
    const int wave = threadIdx.x >> 6, lane = threadIdx.x & 63;
    const int q = lane >> 4, l16 = lane & 15;
    const int Ks = Ktot >> 2;
    const int kbase = wave * Ks;
    const floatx4 z4 = {0.f, 0.f, 0.f, 0.f};
    floatx4 acc[2][2] = {{z4, z4}, {z4, z4}};
    const bf16x8* A0 = (const bf16x8*)(A + (size_t)(m0 + l16) * Ktot);
    const bf16x8* A1 = (const bf16x8*)(A + (size_t)(m0 + 16 + l16) * Ktot);
    const bf16x8* W0 = (const bf16x8*)(W + ((size_t)e * 32 + l16) * Ktot);
    const bf16x8* W1 = (const bf16x8*)(W + ((size_t)e * 32 + 16 + l16) * Ktot);
    for (int k = kbase; k < kbase + Ks; k += 32) {
        int u = (k >> 3) + q;
        bf16x8 a0 = A0[u], a1 = A1[u];
        bf16x8 b0 = W0[u], b1 = W1[u];
        acc[0][0] = __builtin_amdgcn_mfma_f32_16x16x32_bf16(a0, b0, acc[0][0], 0, 0, 0);
        acc[0][1] = __builtin_amdgcn_mfma_f32_16x16x32_bf16(a0, b1, acc[0][1], 0, 0, 0);
        acc[1][0] = __builtin_amdgcn_mfma_f32_16x16x32_bf16(a1, b0, acc[1][0], 0, 0, 0);
        acc[1][1] = __builtin_amdgcn_mfma_f32_16x16x32_bf16(a1, b1, acc[1][1], 0, 0, 0);
    }
    __shared__ float red[4][32][32];
#pragma unroll
    for (int mi = 0; mi < 2; ++mi)
#pragma unroll
        for (int ni = 0; ni < 2; ++ni)
#pragma unroll
            for (int r = 0; r < 4; ++r)
                red[wave][mi * 16 + q * 4 + r][ni * 16 + l16] = acc[mi][ni][r];
    __syncthreads();
    for (int i = threadIdx.x; i < 1024; i += 256) {
        int lr = i >> 5, c = i & 31;
        float s = red[0][lr][c] + red[1][lr][c] + red[2][lr][c] + red[3][lr][c];
        outb[(size_t)(m0 + lr) * 32 + c] = f2b(SCALING * (s + Ab[e * 32 + c]));
    }
}

// ---------------------------------------------------------------------------
// Main GEMM: 128x128 tile, BK=64. global_load_lds width-16 DMA staging into
// XOR-swizzled LDS (swizzle applied on the GLOBAL address side: the DMA's LDS
// dest is fixed wave-uniform-base + lane*16, so we permute which global 16B
// unit each lane fetches; 8-lane groups still cover one 128B segment).
// mfma_f32_16x16x32_bf16, fused LoRA-B (one K=32 MFMA) + fp32 bias.
// fc1: GELU -> bf16 a_g. fc2: fp32 scatter to token-order d_out.
// ---------------------------------------------------------------------------
template <int KTOT, bool IS_FC1>
__global__ __launch_bounds__(256) void k_mlp(
    const unsigned short* __restrict__ Amat,   // [M_MAX, KTOT] bf16
    const unsigned short* __restrict__ Wmat,   // [NOUT, KTOT] bf16 (NT layout)
    const float* __restrict__ bias,            // [NOUT] fp32
    const unsigned short* __restrict__ lora_h, // [M_MAX, 32] pre-scaled bf16
    const unsigned short* __restrict__ lora_B, // [E, NOUT, 32] bf16
    const float* __restrict__ lora_b,          // [E, NOUT] fp32
    const int* __restrict__ hdr, const int* __restrict__ tile_e,
    const int* __restrict__ gather,
    unsigned short* __restrict__ outb,         // fc1: a_g bf16
    float* __restrict__ outf,                  // fc2: d_out fp32
    int NOUT)
{
    const int mtile = blockIdx.y;
    int ntiles = hdr[1]; if (ntiles > TILES_MAX) ntiles = TILES_MAX;
    if (mtile >= ntiles) return;
    const int e = tile_e[mtile] & 7;
    const int h0 = blockIdx.x * 128;
    const int m0 = mtile * 128;
    // 128 rows x 8 units(16B); slot (row, j) holds global column-unit j^(row&7)
    __shared__ bf16x8 As[1024];
    __shared__ bf16x8 Bs[1024];
    const int tid = threadIdx.x;
    const int lane = tid & 63;
    const int q = lane >> 4, l16 = lane & 15;
    const int wave = tid >> 6;
    const int wm = wave & 1, wn = wave >> 1;
    const floatx4 z4 = {0.f, 0.f, 0.f, 0.f};
    floatx4 acc[4][4];
#pragma unroll
    for (int mi = 0; mi < 4; ++mi)
#pragma unroll
        for (int ni = 0; ni < 4; ++ni) acc[mi][ni] = z4;

    const unsigned short* Abase = Amat + (size_t)m0 * KTOT;
    const unsigned short* Bbase = Wmat + (size_t)h0 * KTOT;

    for (int k0 = 0; k0 < KTOT; k0 += 64) {
        // DMA staging: unit s lands at LDS slot s; its global column-unit is
        // (s&7)^(row&7)  ->  slot (row, j) holds global unit j^(row&7).
#pragma unroll
        for (int rnd = 0; rnd < 4; ++rnd) {
            int s = rnd * 256 + tid;
            int row = s >> 3;
            int jj = (s & 7) ^ (row & 7);
            const unsigned short* ga = Abase + (size_t)row * KTOT + k0 + jj * 8;
            const unsigned short* gb = Bbase + (size_t)row * KTOT + k0 + jj * 8;
            GLOAD_LDS16(ga, As + rnd * 256 + wave * 64);
            GLOAD_LDS16(gb, Bs + rnd * 256 + wave * 64);
        }
        __syncthreads();
#pragma unroll
        for (int ka = 0; ka < 2; ++ka) {
            bf16x8 af[4], bfr[4];
#pragma unroll
            for (int mi = 0; mi < 4; ++mi) {
                int row = wm * 64 + mi * 16 + l16;
                af[mi] = As[row * 8 + ((ka * 4 + q) ^ (row & 7))];
            }
#pragma unroll
            for (int ni = 0; ni < 4; ++ni) {
                int row = wn * 64 + ni * 16 + l16;
                bfr[ni] = Bs[row * 8 + ((ka * 4 + q) ^ (row & 7))];
            }
#pragma unroll
            for (int mi = 0; mi < 4; ++mi)
#pragma unroll
                for (int ni = 0; ni < 4; ++ni)
                    acc[mi][ni] = __builtin_amdgcn_mfma_f32_16x16x32_bf16(af[mi], bfr[ni], acc[mi][ni], 0, 0, 0);
        }
        __syncthreads();
    }

    // Fused LoRA-B: one K=32 MFMA per subtile into the same accumulators.
    {
        bf16x8 a2[4], b2[4];
#pragma unroll
        for (int mi = 0; mi < 4; ++mi)
            a2[mi] = *(const bf16x8*)(lora_h + (size_t)(m0 + wm * 64 + mi * 16 + l16) * 32 + q * 8);
#pragma unroll
        for (int ni = 0; ni < 4; ++ni)
            b2[ni] = *(const bf16x8*)(lora_B + ((size_t)e * NOUT + h0 + wn * 64 + ni * 16 + l16) * 32 + q * 8);
#pragma unroll
        for (int mi = 0; mi < 4; ++mi)
#pragma unroll
            for (int ni = 0; ni < 4; ++ni)
                acc[mi][ni] = __builtin_amdgcn_mfma_f32_16x16x32_bf16(a2[mi], b2[ni], acc[mi][ni], 0, 0, 0);
    }

#pragma unroll
    for (int ni = 0; ni < 4; ++ni) {
        int gh = h0 + wn * 64 + ni * 16 + l16;
        float bv = bias[gh] + SCALING * lora_b[e * NOUT + gh];
#pragma unroll
        for (int mi = 0; mi < 4; ++mi) {
#pragma unroll
            for (int r = 0; r < 4; ++r) {
                int gm = m0 + wm * 64 + mi * 16 + q * 4 + r;
                float v = acc[mi][ni][r] + bv;
                if (IS_FC1) {
                    outb[(size_t)gm * NOUT + gh] = f2b(gelu_exact(v));
                } else {
                    int t = gather[gm];
                    if ((unsigned)t < (unsigned)NTOK) outf[(size_t)t * NOUT + gh] = v;
                }
            }
        }
    }
}

// ---------------------------------------------------------------------------
// Workspace layout (bytes).
// ---------------------------------------------------------------------------
#define OFF_IDX      0u
#define OFF_HDR      16384u
#define OFF_TILE     16640u
#define OFF_GATHER   16896u
#define OFF_XG       37376u
#define OFF_HSELB    13144576u
#define OFF_AG       13472256u
#define OFF_HUPB     60658176u
#define OFF_W1B      60985856u
#define OFF_W2B      69374464u
#define OFF_ADB      77763072u
#define OFF_BDB      78287360u
#define OFF_AUB      80384512u
#define OFF_BUB      82481664u
#define WS_NEEDED    83005952u

extern "C" void kernel_launch(void* const* d_in, const int* in_sizes, int n_in,
                              void* d_out, int out_size, void* d_ws, size_t ws_size,
                              hipStream_t stream)
{
    (void)out_size;
    if (ws_size < (size_t)WS_NEEDED) return;
    if (n_in < 15 || in_sizes[0] != NTOK * D_ || in_sizes[3] != H_ * D_ ||
        in_sizes[5] != D_ * H_ || in_sizes[9] != E_ * H_ * R_) return;

    const float* x   = (const float*)d_in[0];
    const float* rw  = (const float*)d_in[1];
    const float* rb  = (const float*)d_in[2];
    const float* w1  = (const float*)d_in[3];
    const float* b1  = (const float*)d_in[4];
    const float* w2  = (const float*)d_in[5];
    const float* b2  = (const float*)d_in[6];
    const float* Ad  = (const float*)d_in[7];
    const float* Abd = (const float*)d_in[8];
    const float* Bd  = (const float*)d_in[9];
    const float* Bbd = (const float*)d_in[10];
    const float* Au  = (const float*)d_in[11];
    const float* Abu = (const float*)d_in[12];
    const float* Bu  = (const float*)d_in[13];
    const float* Bbu = (const float*)d_in[14];
    float* out = (float*)d_out;   // fp32 outputs (reference is all-fp32)
    char* ws = (char*)d_ws;

    int* idx            = (int*)(ws + OFF_IDX);
    int* hdr            = (int*)(ws + OFF_HDR);
    int* tile_e         = (int*)(ws + OFF_TILE);
    int* gather         = (int*)(ws + OFF_GATHER);
    unsigned short* xg  = (unsigned short*)(ws + OFF_XG);
    unsigned short* hsb = (unsigned short*)(ws + OFF_HSELB);
    unsigned short* ag  = (unsigned short*)(ws + OFF_AG);
    unsigned short* hub = (unsigned short*)(ws + OFF_HUPB);
    unsigned short* w1b = (unsigned short*)(ws + OFF_W1B);
    unsigned short* w2b = (unsigned short*)(ws + OFF_W2B);
    unsigned short* Adb = (unsigned short*)(ws + OFF_ADB);
    unsigned short* Bdb = (unsigned short*)(ws + OFF_BDB);
    unsigned short* Aub = (unsigned short*)(ws + OFF_AUB);
    unsigned short* Bub = (unsigned short*)(ws + OFF_BUB);

    // One fused fp32 -> bf16 conversion kernel (11,010,048 elems / 2048 per blk)
    k_cvt_all<<<5376, 256, 0, stream>>>(w1, w2, Ad, Bd, Au, Bu,
                                        w1b, w2b, Adb, Bdb, Aub, Bub);

    k_router<<<NTOK / 4, 256, 0, stream>>>(x, rw, rb, out, idx);
    k_scan<<<1, 256, 0, stream>>>(idx, hdr, tile_e, gather);
    k_gather<<<M_MAX, 128, 0, stream>>>(x, gather, xg);
    k_lora_a2<<<dim3(4, TILES_MAX), 256, 0, stream>>>(xg, Adb, Abd, hdr, tile_e, hsb, D_);
    k_mlp<D_, true><<<dim3(H_ / 128, TILES_MAX), 256, 0, stream>>>(
        xg, w1b, b1, hsb, Bdb, Bbd, hdr, tile_e, gather, ag, nullptr, H_);
    k_lora_a2<<<dim3(4, TILES_MAX), 256, 0, stream>>>(ag, Aub, Abu, hdr, tile_e, hub, H_);
    k_mlp<H_, false><<<dim3(D_ / 128, TILES_MAX), 256, 0, stream>>>(
        ag, w2b, b2, hub, Bub, Bbu, hdr, tile_e, gather, nullptr, out, D_);
}

// Round 10
// 306.715 us; speedup vs baseline: 7.6398x; 1.0765x over previous
//
#include <hip/hip_runtime.h>
#include <hip/hip_bf16.h>
#include <math.h>
#include <stdint.h>

// Problem constants
#define E_ 8
#define R_ 32
#define D_ 1024
#define H_ 4096
#define NTOK 4096          // B*S
#define M_MAX 5120         // padded-token capacity (40 tiles of 128)
#define TILES_MAX 40
#define SCALING 0.03125f   // 1/R

typedef __attribute__((ext_vector_type(8))) __bf16 bf16x8;
typedef __attribute__((ext_vector_type(8))) unsigned short ushort8;
typedef __attribute__((ext_vector_type(4))) float floatx4;

__device__ __forceinline__ unsigned short f2b(float f) {
    union { float f; unsigned int i; } v; v.f = f;
    unsigned int x = v.i;
    x += 0x7fffu + ((x >> 16) & 1u);   // round-to-nearest-even
    return (unsigned short)(x >> 16);
}
// tanh-form GELU (max |err| vs exact erf-GELU ~1.5e-4; propagated to `up`
// ~1e-4 — far under threshold). ~12 VALU vs erff's ~30.
__device__ __forceinline__ float gelu_fast(float v) {
    float u = v * (0.7978845608028654f + 0.0356774080857f * v * v);
    float t = __expf(-2.f * fabsf(u));
    float th = (1.f - t) * __builtin_amdgcn_rcpf(1.f + t);
    th = (u >= 0.f) ? th : -th;
    return 0.5f * v * (1.f + th);
}

#define GLOAD_LDS16(g, l) __builtin_amdgcn_global_load_lds( \
    (const __attribute__((address_space(1))) void*)(g),     \
    (__attribute__((address_space(3))) void*)(l), 16, 0, 0)

// ---------------------------------------------------------------------------
// Kernel 0: fused prep = weight fp32->bf16 conversion (blocks 0..5375) +
// router (blocks 5376..6399, one wave per token, fp32, fp32 outputs).
// ---------------------------------------------------------------------------
__global__ __launch_bounds__(256) void k_prep(
    const float* __restrict__ w1, const float* __restrict__ w2,
    const float* __restrict__ Ad, const float* __restrict__ Bd,
    const float* __restrict__ Au, const float* __restrict__ Bu,
    unsigned short* __restrict__ w1b, unsigned short* __restrict__ w2b,
    unsigned short* __restrict__ Adb, unsigned short* __restrict__ Bdb,
    unsigned short* __restrict__ Aub, unsigned short* __restrict__ Bub,
    const float* __restrict__ x, const float* __restrict__ rw,
    const float* __restrict__ rb,
    float* __restrict__ out, int* __restrict__ idx)
{
    if (blockIdx.x < 5376) {
        long g = ((long)blockIdx.x * 256 + threadIdx.x) * 8;
        const float* src; unsigned short* dst; long off;
        if      (g <  4194304L) { src = w1; dst = w1b; off = 0; }
        else if (g <  8388608L) { src = w2; dst = w2b; off = 4194304L; }
        else if (g <  8650752L) { src = Ad; dst = Adb; off = 8388608L; }
        else if (g <  9699328L) { src = Bd; dst = Bdb; off = 8650752L; }
        else if (g < 10747904L) { src = Au; dst = Aub; off = 9699328L; }
        else                    { src = Bu; dst = Bub; off = 10747904L; }
        long i = g - off;
        float4 a = *(const float4*)(src + i);
        float4 b = *(const float4*)(src + i + 4);
        ushort8 o;
        o[0] = f2b(a.x); o[1] = f2b(a.y); o[2] = f2b(a.z); o[3] = f2b(a.w);
        o[4] = f2b(b.x); o[5] = f2b(b.y); o[6] = f2b(b.z); o[7] = f2b(b.w);
        *(ushort8*)(dst + i) = o;
        return;
    }
    const int wave = threadIdx.x >> 6, lane = threadIdx.x & 63;
    const int t = (blockIdx.x - 5376) * 4 + wave;
    const float4* xr = (const float4*)(x + (size_t)t * D_);
    float4 xv[4];
#pragma unroll
    for (int s = 0; s < 4; ++s) xv[s] = xr[lane + 64 * s];
    float acc[E_];
#pragma unroll
    for (int e = 0; e < E_; ++e) {
        const float4* wr = (const float4*)(rw + (size_t)e * D_);
        float s = 0.f;
#pragma unroll
        for (int u = 0; u < 4; ++u) {
            float4 wv = wr[lane + 64 * u];
            s += xv[u].x * wv.x + xv[u].y * wv.y + xv[u].z * wv.z + xv[u].w * wv.w;
        }
        acc[e] = s;
    }
#pragma unroll
    for (int e = 0; e < E_; ++e) {
#pragma unroll
        for (int m = 32; m > 0; m >>= 1) acc[e] += __shfl_xor(acc[e], m, 64);
        acc[e] += rb[e];
    }
    int best = 0;
#pragma unroll
    for (int e = 1; e < E_; ++e) if (acc[e] > acc[best]) best = e;   // first-max (np.argmax)
    const float mx = acc[best];
    float pr[E_]; float se = 0.f;
#pragma unroll
    for (int e = 0; e < E_; ++e) { pr[e] = expf(acc[e] - mx); se += pr[e]; }
    const float inv = 1.f / se;
    if (lane < E_) {
        float r = pr[lane] * inv;
        out[(size_t)NTOK * D_ + (size_t)t * E_ + lane] = r;
        float maskv = (lane == best) ? 1.f : 0.f;
        out[(size_t)NTOK * D_ + (size_t)NTOK * E_ + (size_t)t * E_ + lane] = (maskv - r) + r;
    }
    if (lane == 0) idx[t] = best;
}

// ---------------------------------------------------------------------------
// Kernel 2: scan (1 block). Deterministic expert-sorted permutation, segments
// padded to multiples of 128 so every GEMM tile has a uniform expert.
// ---------------------------------------------------------------------------
__global__ __launch_bounds__(256) void k_scan(
    const int* __restrict__ idx, int* __restrict__ hdr,
    int* __restrict__ tile_e, int* __restrict__ gather)
{
    __shared__ int cnt[256][E_];
    __shared__ int tot[E_], base[E_];
    const int tid = threadIdx.x;
    for (int m = tid; m < M_MAX; m += 256) gather[m] = -1;
    int c[E_];
#pragma unroll
    for (int e = 0; e < E_; ++e) c[e] = 0;
    for (int t = tid * 16; t < tid * 16 + 16; ++t) c[idx[t] & 7]++;
#pragma unroll
    for (int e = 0; e < E_; ++e) cnt[tid][e] = c[e];
    __syncthreads();
    if (tid < E_) {
        int run = 0;
        for (int i = 0; i < 256; ++i) { int v = cnt[i][tid]; cnt[i][tid] = run; run += v; }
        tot[tid] = run;
    }
    __syncthreads();
    if (tid == 0) {
        int b = 0, tp = 0;
        for (int e = 0; e < E_; ++e) {
            base[e] = b;
            int nt = (tot[e] + 127) >> 7;
            for (int k = 0; k < nt; ++k) tile_e[tp++] = e;
            b += nt << 7;
        }
        hdr[0] = b;       // M_pad
        hdr[1] = tp;      // n_tiles
        for (int k = tp; k < TILES_MAX; ++k) tile_e[k] = 0;
    }
    __syncthreads();
    int p[E_];
#pragma unroll
    for (int e = 0; e < E_; ++e) p[e] = base[e] + cnt[tid][e];
    for (int t = tid * 16; t < tid * 16 + 16; ++t) { int e = idx[t] & 7; gather[p[e]++] = t; }
}

// ---------------------------------------------------------------------------
// Kernel 3: gather x rows (fp32) into expert-sorted bf16 Xg (zeros for pads).
// ---------------------------------------------------------------------------
__global__ __launch_bounds__(128) void k_gather(
    const float* __restrict__ x, const int* __restrict__ gather,
    unsigned short* __restrict__ xg)
{
    const int m = blockIdx.x, tid = threadIdx.x;
    const int t = gather[m];
    ushort8* dst = (ushort8*)(xg + (size_t)m * D_);
    ushort8 o;
    if ((unsigned)t < (unsigned)NTOK) {
        const float4* src = (const float4*)(x + (size_t)t * D_);
        float4 a = src[tid * 2], b = src[tid * 2 + 1];
        o[0] = f2b(a.x); o[1] = f2b(a.y); o[2] = f2b(a.z); o[3] = f2b(a.w);
        o[4] = f2b(b.x); o[5] = f2b(b.y); o[6] = f2b(b.z); o[7] = f2b(b.w);
    } else {
        o = (ushort8)(0);
    }
    dst[tid] = o;
}

// ---------------------------------------------------------------------------
// Kernel 4/6: LoRA A-stage, single pass. Block = 32 m-rows x 32 ranks; the 4
// waves split K, LDS-reduce, add Ab, pre-scale by 1/R, write bf16 [M_MAX,32].
// grid = (4, TILES_MAX).
// ---------------------------------------------------------------------------
__global__ __launch_bounds__(256) void k_lora_a2(
    const unsigned short* __restrict__ A,    // [M_MAX, Ktot] bf16 (Xg or a_g)
    const unsigned short* __restrict__ W,    // [E, 32, Ktot] bf16 (converted)
    const float* __restrict__ Ab,            // [E, 32] fp32
    const int* __restrict__ hdr, const int* __restrict__ tile_e,
    unsigned short* __restrict__ outb,       // [M_MAX, 32] bf16 pre-scaled
    int Ktot)
{
    const int mtile = blockIdx.y;
    int ntiles = hdr[1]; if (ntiles > TILES_MAX) ntiles = TILES_MAX;
    if (mtile >= ntiles) return;
    const int e = tile_e[mtile] & 7;
    const int m0 = mtile * 128 + blockIdx.x * 32;
    const int wave = threadIdx.x >> 6, lane = threadIdx.x & 63;
    const int q = lane >> 4, l16 = lane & 15;
    const int Ks = Ktot >> 2;
    const int kbase = wave * Ks;
    const floatx4 z4 = {0.f, 0.f, 0.f, 0.f};
    floatx4 acc[2][2] = {{z4, z4}, {z4, z4}};
    const bf16x8* A0 = (const bf16x8*)(A + (size_t)(m0 + l16) * Ktot);
    const bf16x8* A1 = (const bf16x8*)(A + (size_t)(m0 + 16 + l16) * Ktot);
    const bf16x8* W0 = (const bf16x8*)(W + ((size_t)e * 32 + l16) * Ktot);
    const bf16x8* W1 = (const bf16x8*)(W + ((size_t)e * 32 + 16 + l16) * Ktot);
    for (int k = kbase; k < kbase + Ks; k += 32) {
        int u = (k >> 3) + q;
        bf16x8 a0 = A0[u], a1 = A1[u];
        bf16x8 b0 = W0[u], b1 = W1[u];
        acc[0][0] = __builtin_amdgcn_mfma_f32_16x16x32_bf16(a0, b0, acc[0][0], 0, 0, 0);
        acc[0][1] = __builtin_amdgcn_mfma_f32_16x16x32_bf16(a0, b1, acc[0][1], 0, 0, 0);
        acc[1][0] = __builtin_amdgcn_mfma_f32_16x16x32_bf16(a1, b0, acc[1][0], 0, 0, 0);
        acc[1][1] = __builtin_amdgcn_mfma_f32_16x16x32_bf16(a1, b1, acc[1][1], 0, 0, 0);
    }
    __shared__ float red[4][32][32];
#pragma unroll
    for (int mi = 0; mi < 2; ++mi)
#pragma unroll
        for (int ni = 0; ni < 2; ++ni)
#pragma unroll
            for (int r = 0; r < 4; ++r)
                red[wave][mi * 16 + q * 4 + r][ni * 16 + l16] = acc[mi][ni][r];
    __syncthreads();
    for (int i = threadIdx.x; i < 1024; i += 256) {
        int lr = i >> 5, c = i & 31;
        float s = red[0][lr][c] + red[1][lr][c] + red[2][lr][c] + red[3][lr][c];
        outb[(size_t)(m0 + lr) * 32 + c] = f2b(SCALING * (s + Ab[e * 32 + c]));
    }
}

// ---------------------------------------------------------------------------
// Main GEMM: 128x128 tile, BK=64, global_load_lds w16 DMA into XOR-swizzled
// LDS (swizzle on the global address side), mfma_f32_16x16x32_bf16.
// NSPLIT-way split-K over blockIdx.z. Split 0 carries fused LoRA-B + bias;
// split 1 writes raw fp32 partials to P. fc1: tanh-GELU -> bf16 a_g.
// fc2 split0: fp32 scatter to token-order d_out.
// ---------------------------------------------------------------------------
template <int KTOT, bool IS_FC1, int NSPLIT>
__global__ __launch_bounds__(256) void k_mlp(
    const unsigned short* __restrict__ Amat,   // [M_MAX, KTOT] bf16
    const unsigned short* __restrict__ Wmat,   // [NOUT, KTOT] bf16 (NT layout)
    const float* __restrict__ bias,            // [NOUT] fp32
    const unsigned short* __restrict__ lora_h, // [M_MAX, 32] pre-scaled bf16
    const unsigned short* __restrict__ lora_B, // [E, NOUT, 32] bf16
    const float* __restrict__ lora_b,          // [E, NOUT] fp32
    const int* __restrict__ hdr, const int* __restrict__ tile_e,
    const int* __restrict__ gather,
    unsigned short* __restrict__ outb,         // fc1: a_g bf16
    float* __restrict__ outf,                  // fc2: d_out fp32
    float* __restrict__ P,                     // fc2 split>0 partials [M_MAX,NOUT]
    int NOUT)
{
    const int mtile = blockIdx.y;
    int ntiles = hdr[1]; if (ntiles > TILES_MAX) ntiles = TILES_MAX;
    if (mtile >= ntiles) return;
    const int e = tile_e[mtile] & 7;
    const int h0 = blockIdx.x * 128;
    const int m0 = mtile * 128;
    const bool extras = (NSPLIT == 1) || (blockIdx.z == 0);
    const int Kslice = KTOT / NSPLIT;
    const int kstart = blockIdx.z * Kslice;
    __shared__ bf16x8 As[1024];
    __shared__ bf16x8 Bs[1024];
    const int tid = threadIdx.x;
    const int lane = tid & 63;
    const int q = lane >> 4, l16 = lane & 15;
    const int wave = tid >> 6;
    const int wm = wave & 1, wn = wave >> 1;
    const floatx4 z4 = {0.f, 0.f, 0.f, 0.f};
    floatx4 acc[4][4];
#pragma unroll
    for (int mi = 0; mi < 4; ++mi)
#pragma unroll
        for (int ni = 0; ni < 4; ++ni) acc[mi][ni] = z4;

    const unsigned short* Abase = Amat + (size_t)m0 * KTOT;
    const unsigned short* Bbase = Wmat + (size_t)h0 * KTOT;

    for (int k0 = kstart; k0 < kstart + Kslice; k0 += 64) {
#pragma unroll
        for (int rnd = 0; rnd < 4; ++rnd) {
            int s = rnd * 256 + tid;
            int row = s >> 3;
            int jj = (s & 7) ^ (row & 7);
            const unsigned short* ga = Abase + (size_t)row * KTOT + k0 + jj * 8;
            const unsigned short* gb = Bbase + (size_t)row * KTOT + k0 + jj * 8;
            GLOAD_LDS16(ga, As + rnd * 256 + wave * 64);
            GLOAD_LDS16(gb, Bs + rnd * 256 + wave * 64);
        }
        __syncthreads();
#pragma unroll
        for (int ka = 0; ka < 2; ++ka) {
            bf16x8 af[4], bfr[4];
#pragma unroll
            for (int mi = 0; mi < 4; ++mi) {
                int row = wm * 64 + mi * 16 + l16;
                af[mi] = As[row * 8 + ((ka * 4 + q) ^ (row & 7))];
            }
#pragma unroll
            for (int ni = 0; ni < 4; ++ni) {
                int row = wn * 64 + ni * 16 + l16;
                bfr[ni] = Bs[row * 8 + ((ka * 4 + q) ^ (row & 7))];
            }
#pragma unroll
            for (int mi = 0; mi < 4; ++mi)
#pragma unroll
                for (int ni = 0; ni < 4; ++ni)
                    acc[mi][ni] = __builtin_amdgcn_mfma_f32_16x16x32_bf16(af[mi], bfr[ni], acc[mi][ni], 0, 0, 0);
        }
        __syncthreads();
    }

    // Fused LoRA-B (split 0 only): one K=32 MFMA per subtile.
    if (extras) {
        bf16x8 a2[4], b2[4];
#pragma unroll
        for (int mi = 0; mi < 4; ++mi)
            a2[mi] = *(const bf16x8*)(lora_h + (size_t)(m0 + wm * 64 + mi * 16 + l16) * 32 + q * 8);
#pragma unroll
        for (int ni = 0; ni < 4; ++ni)
            b2[ni] = *(const bf16x8*)(lora_B + ((size_t)e * NOUT + h0 + wn * 64 + ni * 16 + l16) * 32 + q * 8);
#pragma unroll
        for (int mi = 0; mi < 4; ++mi)
#pragma unroll
            for (int ni = 0; ni < 4; ++ni)
                acc[mi][ni] = __builtin_amdgcn_mfma_f32_16x16x32_bf16(a2[mi], b2[ni], acc[mi][ni], 0, 0, 0);
    }

#pragma unroll
    for (int ni = 0; ni < 4; ++ni) {
        int gh = h0 + wn * 64 + ni * 16 + l16;
        float bv = extras ? (bias[gh] + SCALING * lora_b[e * NOUT + gh]) : 0.f;
#pragma unroll
        for (int mi = 0; mi < 4; ++mi) {
#pragma unroll
            for (int r = 0; r < 4; ++r) {
                int gm = m0 + wm * 64 + mi * 16 + q * 4 + r;
                float v = acc[mi][ni][r] + bv;
                if (IS_FC1) {
                    outb[(size_t)gm * NOUT + gh] = f2b(gelu_fast(v));
                } else if (extras) {
                    int t = gather[gm];
                    if ((unsigned)t < (unsigned)NTOK) outf[(size_t)t * NOUT + gh] = v;
                } else {
                    P[(size_t)gm * NOUT + gh] = v;
                }
            }
        }
    }
}

// ---------------------------------------------------------------------------
// Kernel 8: reduce fc2 split-1 partials into token-order out. One block/row.
// ---------------------------------------------------------------------------
__global__ __launch_bounds__(256) void k_reduce(
    const float* __restrict__ P, const int* __restrict__ gather,
    float* __restrict__ out)
{
    const int m = blockIdx.x;
    const int t = gather[m];
    if ((unsigned)t >= (unsigned)NTOK) return;
    const float4* p4 = (const float4*)(P + (size_t)m * D_);
    float4* o4 = (float4*)(out + (size_t)t * D_);
    int i = threadIdx.x;                      // D_/4 = 256
    float4 a = o4[i], b = p4[i];
    a.x += b.x; a.y += b.y; a.z += b.z; a.w += b.w;
    o4[i] = a;
}

// ---------------------------------------------------------------------------
// Workspace layout (bytes). P (fc2 split-1 partials, 21.0 MB) overlays the
// xg/w1b/Adb/Bdb/hsb region (21.8 MB) — all dead before fc2 runs.
// ---------------------------------------------------------------------------
#define OFF_IDX      0u
#define OFF_HDR      16384u
#define OFF_TILE     16640u
#define OFF_GATHER   16896u        // ends 37376
#define OFF_XG       37376u        // 10,485,760
#define OFF_W1B      10523136u     // 8,388,608
#define OFF_ADB      18911744u     // 524,288
#define OFF_BDB      19436032u     // 2,097,152
#define OFF_HSB      21533184u     // 327,680 -> ends 21,860,864
#define OFF_P        37376u        // 20,971,520 (overlay, ends 21,008,896)
#define OFF_AG       21860864u     // 41,943,040
#define OFF_HUB      63803904u     // 327,680
#define OFF_W2B      64131584u     // 8,388,608
#define OFF_AUB      72520192u     // 2,097,152
#define OFF_BUB      74617344u     // 524,288
#define WS_NEEDED    75141632u

extern "C" void kernel_launch(void* const* d_in, const int* in_sizes, int n_in,
                              void* d_out, int out_size, void* d_ws, size_t ws_size,
                              hipStream_t stream)
{
    (void)out_size;
    if (ws_size < (size_t)WS_NEEDED) return;
    if (n_in < 15 || in_sizes[0] != NTOK * D_ || in_sizes[3] != H_ * D_ ||
        in_sizes[5] != D_ * H_ || in_sizes[9] != E_ * H_ * R_) return;

    const float* x   = (const float*)d_in[0];
    const float* rw  = (const float*)d_in[1];
    const float* rb  = (const float*)d_in[2];
    const float* w1  = (const float*)d_in[3];
    const float* b1  = (const float*)d_in[4];
    const float* w2  = (const float*)d_in[5];
    const float* b2  = (const float*)d_in[6];
    const float* Ad  = (const float*)d_in[7];
    const float* Abd = (const float*)d_in[8];
    const float* Bd  = (const float*)d_in[9];
    const float* Bbd = (const float*)d_in[10];
    const float* Au  = (const float*)d_in[11];
    const float* Abu = (const float*)d_in[12];
    const float* Bu  = (const float*)d_in[13];
    const float* Bbu = (const float*)d_in[14];
    float* out = (float*)d_out;
    char* ws = (char*)d_ws;

    int* idx            = (int*)(ws + OFF_IDX);
    int* hdr            = (int*)(ws + OFF_HDR);
    int* tile_e         = (int*)(ws + OFF_TILE);
    int* gather         = (int*)(ws + OFF_GATHER);
    unsigned short* xg  = (unsigned short*)(ws + OFF_XG);
    unsigned short* hsb = (unsigned short*)(ws + OFF_HSB);
    unsigned short* ag  = (unsigned short*)(ws + OFF_AG);
    unsigned short* hub = (unsigned short*)(ws + OFF_HUB);
    unsigned short* w1b = (unsigned short*)(ws + OFF_W1B);
    unsigned short* w2b = (unsigned short*)(ws + OFF_W2B);
    unsigned short* Adb = (unsigned short*)(ws + OFF_ADB);
    unsigned short* Bdb = (unsigned short*)(ws + OFF_BDB);
    unsigned short* Aub = (unsigned short*)(ws + OFF_AUB);
    unsigned short* Bub = (unsigned short*)(ws + OFF_BUB);
    float* P            = (float*)(ws + OFF_P);

    // prep = weight cvt (5376 blocks) + router (1024 blocks)
    k_prep<<<6400, 256, 0, stream>>>(w1, w2, Ad, Bd, Au, Bu,
                                     w1b, w2b, Adb, Bdb, Aub, Bub,
                                     x, rw, rb, out, idx);
    k_scan<<<1, 256, 0, stream>>>(idx, hdr, tile_e, gather);
    k_gather<<<M_MAX, 128, 0, stream>>>(x, gather, xg);
    k_lora_a2<<<dim3(4, TILES_MAX), 256, 0, stream>>>(xg, Adb, Abd, hdr, tile_e, hsb, D_);
    k_mlp<D_, true, 1><<<dim3(H_ / 128, TILES_MAX, 1), 256, 0, stream>>>(
        xg, w1b, b1, hsb, Bdb, Bbd, hdr, tile_e, gather, ag, nullptr, nullptr, H_);
    k_lora_a2<<<dim3(4, TILES_MAX), 256, 0, stream>>>(ag, Aub, Abu, hdr, tile_e, hub, H_);
    k_mlp<H_, false, 2><<<dim3(D_ / 128, TILES_MAX, 2), 256, 0, stream>>>(
        ag, w2b, b2, hub, Bub, Bbu, hdr, tile_e, gather, nullptr, out, P, D_);
    k_reduce<<<M_MAX, 256, 0, stream>>>(P, gather, out);
}